// Round 1
// baseline (97.245 us; speedup 1.0000x reference)
//
#include <hip/hip_runtime.h>

#define N_ATOMS 10000
#define N_EDGES 200000
#define EB   32          // edges staged per batch
#define ROWF 44          // padded LDS row stride in floats (176 B, 16B-aligned, banks 12l%32 -> all 32)
#define PI_F 3.14159265358979323846f
#define W_F  0.6283185307179586f   // pi/5 in f32

// ---- kernel A: precompute segment starts (starts[a] = lower_bound(seg_i, a)) ----
__global__ __launch_bounds__(256) void seg_starts_kernel(
    const int* __restrict__ seg_i, int* __restrict__ starts)
{
    const int a = blockIdx.x * blockDim.x + threadIdx.x;
    if (a > N_ATOMS) return;
    int lo = 0, hi = N_EDGES;
    while (lo < hi) {
        int mid = (lo + hi) >> 1;
        if (seg_i[mid] < a) lo = mid + 1; else hi = mid;
    }
    starts[a] = lo;
}

// ---- accumulation mapping table: 43 active lanes, each owns (m-pair, 4n, 4c) ----
// packed word a: n0[0:4] | aidx[5:10] | w[11:13] | m1[14] | nl4[15:21] | stride[22:31]
// word b: off0 = base + (m0*nl + n0)*4   (floats)
#define TE(n0,aidx,w,m1,nl4,str,off) \
  {(unsigned)((n0)|((aidx)<<5)|((w)<<11)|((m1)<<14)|((nl4)<<15)|((unsigned)(str)<<22)), (unsigned)(off)}
__device__ const uint2 TBL[43] = {
    // l0: nl=20 stride 80, angular col 20 (m1 ghost reads zero-pad col 21)
    TE( 0,20,4,0,80, 80,      0), TE( 4,20,4,0,80, 80,     16),
    TE( 8,20,4,0,80, 80,     32), TE(12,20,4,0,80, 80,     48),
    TE(16,20,4,0,80, 80,     64),
    // l1: nl=18 stride 216, base 800000, ang cols 22,23,24 (pad 25)
    TE( 0,22,4,1,72,216, 800000), TE( 4,22,4,1,72,216, 800016),
    TE( 8,22,4,1,72,216, 800032), TE(12,22,4,1,72,216, 800048),
    TE(16,22,2,1,72,216, 800064),
    TE( 0,24,4,0,72,216, 800144), TE( 4,24,4,0,72,216, 800160),
    TE( 8,24,4,0,72,216, 800176), TE(12,24,4,0,72,216, 800192),
    TE(16,24,2,0,72,216, 800208),
    // l2: nl=16 stride 320, base 2960000, ang cols 26..30 (pad 31)
    TE( 0,26,4,1,64,320,2960000), TE( 4,26,4,1,64,320,2960016),
    TE( 8,26,4,1,64,320,2960032), TE(12,26,4,1,64,320,2960048),
    TE( 0,28,4,1,64,320,2960128), TE( 4,28,4,1,64,320,2960144),
    TE( 8,28,4,1,64,320,2960160), TE(12,28,4,1,64,320,2960176),
    TE( 0,30,4,0,64,320,2960256), TE( 4,30,4,0,64,320,2960272),
    TE( 8,30,4,0,64,320,2960288), TE(12,30,4,0,64,320,2960304),
    // l3: nl=14 stride 392, base 6160000, ang cols 32..38 (pad 39)
    TE( 0,32,4,1,56,392,6160000), TE( 4,32,4,1,56,392,6160016),
    TE( 8,32,4,1,56,392,6160032), TE(12,32,2,1,56,392,6160048),
    TE( 0,34,4,1,56,392,6160112), TE( 4,34,4,1,56,392,6160128),
    TE( 8,34,4,1,56,392,6160144), TE(12,34,2,1,56,392,6160160),
    TE( 0,36,4,1,56,392,6160224), TE( 4,36,4,1,56,392,6160240),
    TE( 8,36,4,1,56,392,6160256), TE(12,36,2,1,56,392,6160272),
    TE( 0,38,4,0,56,392,6160336), TE( 4,38,4,0,56,392,6160352),
    TE( 8,38,4,0,56,392,6160368), TE(12,38,2,0,56,392,6160384),
};

// ---- kernel B: one 64-thread (single-wave) block per atom ----
__global__ __launch_bounds__(64) void sph_expand_kernel(
    const float* __restrict__ R,
    const int*   __restrict__ starts,
    const int*   __restrict__ idx_j,
    const int*   __restrict__ species,
    const float* __restrict__ emb,
    float*       __restrict__ out)
{
    __shared__ float feat[EB * ROWF];   // 5632 B
    const int atom = blockIdx.x;
    const int tid  = threadIdx.x;

    // per-lane output mapping (lanes 43..63 clamp to entry 42, never store)
    const uint2 tb = TBL[tid < 43 ? tid : 42];
    const int n0     = tb.x & 31;
    const int aidx   = (tb.x >> 5)  & 63;
    const int w      = (tb.x >> 11) & 7;
    const int m1     = (tb.x >> 14) & 1;
    const int nl4    = (tb.x >> 15) & 127;
    const int stride = (int)(tb.x >> 22);
    const bool active = (tid < 43);

    float4 a00{0,0,0,0}, a01{0,0,0,0}, a02{0,0,0,0}, a03{0,0,0,0};
    float4 a10{0,0,0,0}, a11{0,0,0,0}, a12{0,0,0,0}, a13{0,0,0,0};

    const int start = starts[atom];
    const int end   = starts[atom + 1];

    for (int e0 = start; e0 < end; e0 += EB) {
        const int cnt = min(EB, end - e0);
        __syncthreads();   // single-wave wg: compiles to lgkmcnt drain only
        if (tid < cnt) {
            const int g  = e0 + tid;
            const int jj = idx_j[g];
            const float x = R[3*g + 0];
            const float y = R[3*g + 1];
            const float z = R[3*g + 2];
            const int sidx = species[jj];
            const float r   = sqrtf(x*x + y*y + z*z);
            const float inv = 1.0f / (r + 1e-12f);
            const float ux = x*inv, uy = y*inv, uz = z*inv;
            const float4 spv = *(const float4*)&emb[4 * sidx];

            // one sin + one cos; harmonics via Chebyshev recurrence (identical math to prev version)
            const float t1 = W_F * r;
            const float s1 = sinf(t1);
            const float c1 = cosf(t1);
            const float fc = (r < 5.0f) ? (0.5f * (c1 + 1.0f)) : 0.0f;
            const float c2x = 2.0f * c1;

            float rb[20];
            {
                float sk_2 = 0.0f, sk_1 = s1;
                rb[0] = s1 * fc;
                #pragma unroll
                for (int k = 1; k < 20; ++k) {
                    const float sk = c2x * sk_1 - sk_2;
                    rb[k] = sk * fc;
                    sk_2 = sk_1; sk_1 = sk;
                }
            }

            const float x2 = ux*ux, y2 = uy*uy, z2 = uz*uz;
            const float c1a = 0.4886025119029199f;
            const float c2a = 1.0925484305920792f;
            float an[16];
            an[0]  = 0.28209479177387814f;
            an[1]  = c1a * uy;
            an[2]  = c1a * uz;
            an[3]  = c1a * ux;
            an[4]  = c2a * ux * uy;
            an[5]  = c2a * uy * uz;
            an[6]  = 0.31539156525252005f * (3.0f*z2 - 1.0f);
            an[7]  = c2a * ux * uz;
            an[8]  = 0.5462742152960396f * (x2 - y2);
            an[9]  = 0.5900435899266435f * uy * (3.0f*x2 - y2);
            an[10] = 2.890611442640554f  * ux * uy * uz;
            an[11] = 0.4570457994644658f * uy * (5.0f*z2 - 1.0f);
            an[12] = 0.3731763325901154f * uz * (5.0f*z2 - 3.0f);
            an[13] = 0.4570457994644658f * ux * (5.0f*z2 - 1.0f);
            an[14] = 1.445305721320277f  * uz * (x2 - y2);
            an[15] = 0.5900435899266435f * ux * (x2 - 3.0f*y2);

            // padded layout: [0..19] radial | 20 an0 0 | 22,23,24 an1..3 0 |
            // 26..30 an4..8 0 | 32..38 an9..15 0 | 40..43 spv
            float4* row = (float4*)&feat[tid * ROWF];
            row[0]  = float4{rb[0],  rb[1],  rb[2],  rb[3]};
            row[1]  = float4{rb[4],  rb[5],  rb[6],  rb[7]};
            row[2]  = float4{rb[8],  rb[9],  rb[10], rb[11]};
            row[3]  = float4{rb[12], rb[13], rb[14], rb[15]};
            row[4]  = float4{rb[16], rb[17], rb[18], rb[19]};
            row[5]  = float4{an[0],  0.0f,   an[1],  an[2]};
            row[6]  = float4{an[3],  0.0f,   an[4],  an[5]};
            row[7]  = float4{an[6],  an[7],  an[8],  0.0f};
            row[8]  = float4{an[9],  an[10], an[11], an[12]};
            row[9]  = float4{an[13], an[14], an[15], 0.0f};
            row[10] = spv;
        }
        __syncthreads();

        // 3 LDS reads per edge per wave: b128 radial quad, b64 angular pair, b128 species
        const float* f = feat;
        for (int s = 0; s < cnt; ++s, f += ROWF) {
            const float4 rv = *(const float4*)(f + n0);
            const float2 av = *(const float2*)(f + aidx);
            const float4 sv = *(const float4*)(f + 40);
            float q;
            q = rv.x*av.x; a00.x += q*sv.x; a00.y += q*sv.y; a00.z += q*sv.z; a00.w += q*sv.w;
            q = rv.y*av.x; a01.x += q*sv.x; a01.y += q*sv.y; a01.z += q*sv.z; a01.w += q*sv.w;
            q = rv.z*av.x; a02.x += q*sv.x; a02.y += q*sv.y; a02.z += q*sv.z; a02.w += q*sv.w;
            q = rv.w*av.x; a03.x += q*sv.x; a03.y += q*sv.y; a03.z += q*sv.z; a03.w += q*sv.w;
            q = rv.x*av.y; a10.x += q*sv.x; a10.y += q*sv.y; a10.z += q*sv.z; a10.w += q*sv.w;
            q = rv.y*av.y; a11.x += q*sv.x; a11.y += q*sv.y; a11.z += q*sv.z; a11.w += q*sv.w;
            q = rv.z*av.y; a12.x += q*sv.x; a12.y += q*sv.y; a12.z += q*sv.z; a12.w += q*sv.w;
            q = rv.w*av.y; a13.x += q*sv.x; a13.y += q*sv.y; a13.z += q*sv.z; a13.w += q*sv.w;
        }
    }

    if (active) {
        float* o = out + (size_t)tb.y + (size_t)atom * (size_t)stride;
        *(float4*)(o + 0) = a00;
        *(float4*)(o + 4) = a01;
        if (w == 4) { *(float4*)(o + 8) = a02; *(float4*)(o + 12) = a03; }
        if (m1) {
            float* o1 = o + nl4;
            *(float4*)(o1 + 0) = a10;
            *(float4*)(o1 + 4) = a11;
            if (w == 4) { *(float4*)(o1 + 8) = a12; *(float4*)(o1 + 12) = a13; }
        }
    }
}

extern "C" void kernel_launch(void* const* d_in, const int* in_sizes, int n_in,
                              void* d_out, int out_size, void* d_ws, size_t ws_size,
                              hipStream_t stream) {
    const float* R    = (const float*)d_in[0];
    const int*   i_   = (const int*)  d_in[1];
    const int*   j_   = (const int*)  d_in[2];
    const int*   sp   = (const int*)  d_in[3];
    const float* emb  = (const float*)d_in[4];
    float* out = (float*)d_out;
    int*   starts = (int*)d_ws;   // 10001 ints

    seg_starts_kernel<<<(N_ATOMS + 256) / 256, 256, 0, stream>>>(i_, starts);
    sph_expand_kernel<<<N_ATOMS, 64, 0, stream>>>(R, starts, j_, sp, emb, out);
}